// Round 16
// baseline (897.538 us; speedup 1.0000x reference)
//
#include <hip/hip_runtime.h>
#include <hip/hip_bf16.h>

// MoE FFN: B=4,T=2048,D=1024,F=4096,E=8,topK=2 ; N=8192 tokens, NPAIR=16384
#define N_TOK  8192
#define DIM    1024
#define FFDIM  4096
#define NEXP   8
#define NPAIR  16384
#define MAXTILE 144   // >= sum_e ceil(cnt_e/128) <= 136

typedef unsigned short u16;
typedef unsigned int u32;
typedef __attribute__((ext_vector_type(8))) short bf16x8;   // 8 bf16 = 4 VGPR
typedef __attribute__((ext_vector_type(8))) unsigned short ushort8;
typedef __attribute__((ext_vector_type(4))) float f32x4;

__device__ __forceinline__ u16 f2bf(float f) {
  unsigned u = __float_as_uint(f);
  u += 0x7fffu + ((u >> 16) & 1u);      // round-to-nearest-even
  return (u16)(u >> 16);
}

// async global->LDS, 16B per lane. LDS dest = wave-uniform base + lane*16.
__device__ __forceinline__ void gl16(const void* g, void* l) {
  __builtin_amdgcn_global_load_lds(
      (const __attribute__((address_space(1))) u32*)g,
      (__attribute__((address_space(3))) u32*)l, 16, 0, 0);
}

// ------- transpose+convert: src fp32 [R][C] -> dst bf16 [C][R], per expert, 64x64 tiles -------
template <int R, int C>
__global__ __launch_bounds__(256) void k_tr64(const float* __restrict__ src,
                                              u16* __restrict__ dst) {
  __shared__ float t[64][65];
  const size_t eoff = (size_t)blockIdx.z * R * C;
  const int c0 = blockIdx.x * 64, r0 = blockIdx.y * 64;
  const int tid = threadIdx.x;
  {
    const int rr = tid >> 4, c4 = (tid & 15) * 4;
#pragma unroll
    for (int i = 0; i < 4; i++) {
      float4 v = *(const float4*)(src + eoff + (size_t)(r0 + rr + 16 * i) * C + c0 + c4);
      t[rr + 16 * i][c4] = v.x; t[rr + 16 * i][c4 + 1] = v.y;
      t[rr + 16 * i][c4 + 2] = v.z; t[rr + 16 * i][c4 + 3] = v.w;
    }
  }
  __syncthreads();
  {
    const int seg = tid & 7;            // 8 bf16 chunk within a dst row
#pragma unroll
    for (int i = 0; i < 2; i++) {
      int cc = (tid >> 3) + 32 * i;     // dst row (= src col)
      ushort8 o;
#pragma unroll
      for (int j = 0; j < 8; j++) o[j] = f2bf(t[seg * 8 + j][cc]);
      *(ushort8*)(dst + eoff + (size_t)(c0 + cc) * R + r0 + seg * 8) = o;
    }
  }
}

// ---------- router (fp64 logits, top-2, fp32 softmax) + fused x fp32->bf16 ----------
__global__ __launch_bounds__(256) void k_router(const float* __restrict__ x,
                                                const float* __restrict__ rw,
                                                u16* __restrict__ xb,
                                                int* __restrict__ tki,
                                                float* __restrict__ tkw,
                                                int* __restrict__ counts) {
  int lane = threadIdx.x & 63;
  int tok = blockIdx.x * 4 + (threadIdx.x >> 6);   // one wave per token
  const float* xr = x + (size_t)tok * DIM;
  u16* xbr = xb + (size_t)tok * DIM;
  double acc[NEXP];
#pragma unroll
  for (int e = 0; e < NEXP; e++) acc[e] = 0.0;
  for (int i = lane * 4; i < DIM; i += 256) {
    float4 xv = *(const float4*)(xr + i);
    ushort4 o;
    o.x = f2bf(xv.x); o.y = f2bf(xv.y); o.z = f2bf(xv.z); o.w = f2bf(xv.w);
    *(ushort4*)(xbr + i) = o;
#pragma unroll
    for (int e = 0; e < NEXP; e++) {
      float4 wv = *(const float4*)(rw + e * DIM + i);
      acc[e] += (double)xv.x * (double)wv.x + (double)xv.y * (double)wv.y +
                (double)xv.z * (double)wv.z + (double)xv.w * (double)wv.w;
    }
  }
#pragma unroll
  for (int e = 0; e < NEXP; e++) {
#pragma unroll
    for (int off = 32; off > 0; off >>= 1) acc[e] += __shfl_down(acc[e], off);
  }
  if (lane == 0) {
    int i0 = 0; double v0 = acc[0];
#pragma unroll
    for (int e = 1; e < NEXP; e++) if (acc[e] > v0) { v0 = acc[e]; i0 = e; }
    int i1 = -1; double v1 = -1e300;
#pragma unroll
    for (int e = 0; e < NEXP; e++)
      if (e != i0 && acc[e] > v1) { v1 = acc[e]; i1 = e; }
    float d = expf((float)(v1 - v0));   // v1 <= v0
    float s = 1.f + d;
    tki[tok * 2] = i0; tki[tok * 2 + 1] = i1;
    tkw[tok * 2] = 1.f / s; tkw[tok * 2 + 1] = d / s;
    atomicAdd(&counts[i0], 1); atomicAdd(&counts[i1], 1);
  }
}

// scan + build 128-row M-tile table, parallel. tiles[t] = (expert, pair_base)
__global__ void k_scan(const int* __restrict__ counts, int* __restrict__ offs,
                       int* __restrict__ curs, int2* __restrict__ tiles,
                       int* __restrict__ ntiles) {
  __shared__ int soff[NEXP + 1];
  __shared__ int stil[NEXP + 1];
  const int lane = threadIdx.x;    // 64 threads
  if (lane == 0) {
    int s = 0, t = 0;
    for (int e = 0; e < NEXP; e++) {
      soff[e] = s; stil[e] = t;
      offs[e] = s; curs[e] = 0;
      s += counts[e]; t += (counts[e] + 127) >> 7;
    }
    soff[NEXP] = s; stil[NEXP] = t;
    offs[NEXP] = s; *ntiles = t;
  }
  __syncthreads();
  const int T = stil[NEXP];
  for (int t = lane; t < T; t += 64) {
    int e = 0;
#pragma unroll
    for (int q = 1; q < NEXP; q++) if (t >= stil[q]) e = q;
    int2 v; v.x = e; v.y = soff[e] + (t - stil[e]) * 128;
    tiles[t] = v;
  }
}

__global__ __launch_bounds__(256) void k_scatter(const int* __restrict__ tki,
                                                 const float* __restrict__ tkw,
                                                 const int* __restrict__ offs,
                                                 int* __restrict__ curs,
                                                 int* __restrict__ ptok,
                                                 float* __restrict__ pgate) {
  int tok = blockIdx.x * 256 + threadIdx.x;
#pragma unroll
  for (int k = 0; k < 2; k++) {
    int e = tki[tok * 2 + k];
    int slot = atomicAdd(&curs[e], 1);
    int pos = offs[e] + slot;
    ptok[pos] = tok;
    pgate[pos] = tkw[tok * 2 + k];
  }
}

// =====================================================================================
// grouped GEMM, r12 structure with BK=128: 128x128 tile, 4 waves, single 64KB LDS
// buffer, 2-barrier drain K-loop. BK 64->128 halves the number of drain stalls per
// GEMM (fixed ~1800cy latency per step amortized over 2x MFMA work). Residency target
// 2 blocks/CU (measured cap of this structure; 64KB LDS does not reduce it — m132's
// BK=128 regression was a 3->2 residency cut, we are already at 2).
// Rows are 256B (128 bf16); stored[r][s16] = global[r][s16 ^ (r&15)] (pre-swizzled
// global source, linear LDS dest, swizzled ds_read — rule #21). Read conflicts: 16
// lanes hit slot*4 mod 32 banks -> 2-way only (free, m136).
// XCD-bijective remap: all N-blocks of an M-tile co-reside on one XCD's L2.
// MODE 0: H[p][f] = gelu(x[tok(p)] @ w1t[e][f])          NY=32, K=1024, NT=8
// MODE 1: out[tok(p)][d] += gate(p)*(H[p] @ w2t[e][d])   NY=8,  K=4096, NT=32
// =====================================================================================
template <int MODE>
__global__ __launch_bounds__(256, 2) void k_gemm(const u16* __restrict__ Abase,
                                                 const u16* __restrict__ Ball,
                                                 const int* __restrict__ offs,
                                                 const int2* __restrict__ tiles,
                                                 const int* __restrict__ ntiles,
                                                 const int* __restrict__ ptok,
                                                 const float* __restrict__ pgate,
                                                 u16* __restrict__ Hout,
                                                 float* __restrict__ out) {
  constexpr int KSZ = (MODE == 0) ? DIM : FFDIM;
  constexpr int NSZ = (MODE == 0) ? FFDIM : DIM;
  constexpr int NY = NSZ / 128;                  // 32 / 8
  constexpr int NWG = MAXTILE * NY;              // 4608 / 1152 (both %8==0)
  constexpr int CPX = NWG / 8;

  // XCD-bijective remap, ny innermost: same-A blocks contiguous within an XCD chunk.
  const int orig = (int)blockIdx.y * MAXTILE + (int)blockIdx.x;
  const int wgid = (orig & 7) * CPX + (orig >> 3);
  const int mt = wgid / NY;
  const int ny = wgid - mt * NY;
  if (mt >= *ntiles) return;

  const int2 te = tiles[mt];
  const int e = te.x;
  const int pair_base = te.y;
  const int pair_last = offs[e + 1] - 1;
  const int n0 = ny * 128;

  __shared__ __align__(16) char lds[65536];      // A 32KB + B 32KB
  char* ldsA = lds;
  char* ldsB = lds + 32768;

  const int tid = threadIdx.x;
  const int lane = tid & 63;
  const int w = tid >> 6;
  const int wm = w >> 1, wn = w & 1;             // 2x2 wave grid, wave output 64x64

  const u16* Bexp = Ball + (size_t)e * KSZ * NSZ;

  // staging: each gl16 covers 4 rows x 16 slots of 16B (1KB). Wave w owns rows
  // [w*32, w*32+32) of both A and B -> 8 gl16 each. lane l -> row chunk*4+(l>>4),
  // stored slot l&15; global slot = (l&15) ^ (row&15).
  const char* aSrc[8];
  const char* bSrc[8];
#pragma unroll
  for (int i = 0; i < 8; i++) {
    int r = w * 32 + i * 4 + (lane >> 4);
    int soff = (((lane & 15) ^ (r & 15)) << 4);
    int p = pair_base + r; if (p > pair_last) p = pair_last;   // clamp tail
    int arow = (MODE == 0) ? ptok[p] : p;
    aSrc[i] = (const char*)(Abase + (size_t)arow * KSZ) + soff;
    bSrc[i] = (const char*)(Bexp + (size_t)(n0 + r) * KSZ) + soff;
  }

  f32x4 acc[4][4] = {};

  constexpr int NT = KSZ / 128;
#pragma unroll 1
  for (int kt = 0; kt < NT; ++kt) {
    __syncthreads();   // previous tile fully consumed
#pragma unroll
    for (int i = 0; i < 8; i++) {
      gl16(aSrc[i], ldsA + (w * 32 + i * 4) * 256);
      gl16(bSrc[i], ldsB + (w * 32 + i * 4) * 256);
      aSrc[i] += 256; bSrc[i] += 256;
    }
    __syncthreads();   // drains vmcnt(0): tile visible
#pragma unroll
    for (int kk = 0; kk < 4; kk++) {
      bf16x8 av[4], bv[4];
#pragma unroll
      for (int fm = 0; fm < 4; fm++) {
        int row = wm * 64 + fm * 16 + (lane & 15);
        int slot = (kk * 4 + (lane >> 4)) ^ (row & 15);
        av[fm] = *(const bf16x8*)(ldsA + row * 256 + slot * 16);
      }
#pragma unroll
      for (int fn = 0; fn < 4; fn++) {
        int row = wn * 64 + fn * 16 + (lane & 15);
        int slot = (kk * 4 + (lane >> 4)) ^ (row & 15);
        bv[fn] = *(const bf16x8*)(ldsB + row * 256 + slot * 16);
      }
#pragma unroll
      for (int fm = 0; fm < 4; fm++)
#pragma unroll
        for (int fn = 0; fn < 4; fn++)
          acc[fm][fn] = __builtin_amdgcn_mfma_f32_16x16x32_bf16(av[fm], bv[fn],
                                                                acc[fm][fn], 0, 0, 0);
    }
  }

  // ---- epilogue. C/D layout (m89-verified): col = lane&15, row = (lane>>4)*4 + j ----
  if (MODE == 0) {
    // Coalesced H write via per-wave LDS restage (padded 68-f32 rows).
    // FULLY UNROLLED m: acc indices stay compile-time (rule #20).
    __syncthreads();   // all waves done reading ldsA/ldsB before reuse
    float* lw = (float*)(lds + w * 4352);        // 16 rows x 68 f32, wave-private
#pragma unroll
    for (int m = 0; m < 4; m++) {
#pragma unroll
      for (int fn = 0; fn < 4; fn++)
#pragma unroll
        for (int j = 0; j < 4; j++)
          lw[(((lane >> 4) << 2) + j) * 68 + fn * 16 + (lane & 15)] = acc[m][fn][j];
      asm volatile("s_waitcnt lgkmcnt(0)" ::: "memory");  // wave-private ds ordering
      const int r = lane >> 2;                   // 0..15, 4 lanes per row
      const int c0 = (lane & 3) * 16;
      const int p = pair_base + wm * 64 + m * 16 + r;
      f32x4 v0 = *(const f32x4*)(lw + r * 68 + c0);
      f32x4 v1 = *(const f32x4*)(lw + r * 68 + c0 + 4);
      f32x4 v2 = *(const f32x4*)(lw + r * 68 + c0 + 8);
      f32x4 v3 = *(const f32x4*)(lw + r * 68 + c0 + 12);
      asm volatile("s_waitcnt lgkmcnt(0)" ::: "memory");
      if (p <= pair_last) {
        ushort8 o0, o1;
#pragma unroll
        for (int k = 0; k < 4; k++) {
          float h;
          h = v0[k]; o0[k]     = f2bf(0.5f * h * (1.f + erff(h * 0.70710678118654752f)));
          h = v1[k]; o0[k + 4] = f2bf(0.5f * h * (1.f + erff(h * 0.70710678118654752f)));
          h = v2[k]; o1[k]     = f2bf(0.5f * h * (1.f + erff(h * 0.70710678118654752f)));
          h = v3[k]; o1[k + 4] = f2bf(0.5f * h * (1.f + erff(h * 0.70710678118654752f)));
        }
        u16* hp = Hout + (size_t)p * FFDIM + n0 + wn * 64 + c0;
        *(ushort8*)hp = o0;
        *(ushort8*)(hp + 8) = o1;
      }
    }
  } else {
#pragma unroll
    for (int m = 0; m < 4; m++) {
      int rbase = wm * 64 + m * 16 + ((lane >> 4) << 2);
#pragma unroll
      for (int j = 0; j < 4; j++) {
        int p = pair_base + rbase + j;
        if (p > pair_last) continue;
        float gate = pgate[p];
        int tokr = ptok[p];
#pragma unroll
        for (int fn = 0; fn < 4; fn++) {
          int col = n0 + wn * 64 + fn * 16 + (lane & 15);
          atomicAdd(&out[(size_t)tokr * DIM + col], acc[m][fn][j] * gate);
        }
      }
    }
  }
}

// ---------------- launcher ----------------
extern "C" void kernel_launch(void* const* d_in, const int* in_sizes, int n_in,
                              void* d_out, int out_size, void* d_ws, size_t ws_size,
                              hipStream_t stream) {
  const float* x  = (const float*)d_in[0];
  const float* rw = (const float*)d_in[1];
  const float* w1 = (const float*)d_in[2];
  const float* w2 = (const float*)d_in[3];
  float* out = (float*)d_out;

  char* ws = (char*)d_ws;
  u16* xb   = (u16*)ws;  ws += (size_t)N_TOK * DIM * 2;          // 16.8 MB
  u16* w1t  = (u16*)ws;  ws += (size_t)NEXP * FFDIM * DIM * 2;   // 67 MB   [E][F][D]
  u16* w2t  = (u16*)ws;  ws += (size_t)NEXP * DIM * FFDIM * 2;   // 67 MB   [E][D][F]
  u16* H    = (u16*)ws;  ws += (size_t)NPAIR * FFDIM * 2;        // 134 MB  [NPAIR][F]
  int*   ptok  = (int*)ws;   ws += NPAIR * 4;
  float* pgate = (float*)ws; ws += NPAIR * 4;
  int*   tki   = (int*)ws;   ws += N_TOK * 2 * 4;
  float* tkw   = (float*)ws; ws += N_TOK * 2 * 4;
  int*   counts = (int*)ws;  ws += NEXP * 4;
  int*   offs   = (int*)ws;  ws += (NEXP + 1) * 4;
  int*   curs   = (int*)ws;  ws += NEXP * 4;
  int2*  tiles  = (int2*)ws; ws += MAXTILE * 8;
  int*   ntiles = (int*)ws;  ws += 4;

  hipMemsetAsync(counts, 0, (NEXP + (NEXP + 1) + NEXP) * 4, stream);
  hipMemsetAsync(d_out, 0, (size_t)N_TOK * DIM * 4, stream);

  k_router<<<N_TOK / 4, 256, 0, stream>>>(x, rw, xb, tki, tkw, counts);
  k_tr64<DIM, FFDIM><<<dim3(FFDIM / 64, DIM / 64, NEXP), 256, 0, stream>>>(w1, w1t);
  k_tr64<FFDIM, DIM><<<dim3(DIM / 64, FFDIM / 64, NEXP), 256, 0, stream>>>(w2, w2t);
  k_scan<<<1, 64, 0, stream>>>(counts, offs, curs, tiles, ntiles);
  k_scatter<<<N_TOK / 256, 256, 0, stream>>>(tki, tkw, offs, curs, ptok, pgate);
  // fc1: NY=32 N-tiles; fc2: NY=8 N-tiles
  k_gemm<0><<<dim3(MAXTILE, 32), 256, 0, stream>>>(
      xb, w1t, offs, tiles, ntiles, ptok, pgate, H, nullptr);
  k_gemm<1><<<dim3(MAXTILE, 8), 256, 0, stream>>>(
      H, w2t, offs, tiles, ntiles, ptok, pgate, nullptr, out);
}

// Round 17
// 698.225 us; speedup vs baseline: 1.2855x; 1.2855x over previous
//
#include <hip/hip_runtime.h>
#include <hip/hip_bf16.h>

// MoE FFN: B=4,T=2048,D=1024,F=4096,E=8,topK=2 ; N=8192 tokens, NPAIR=16384
#define N_TOK  8192
#define DIM    1024
#define FFDIM  4096
#define NEXP   8
#define NPAIR  16384
#define MAXTILE 144   // >= sum_e ceil(cnt_e/128) <= 136

typedef unsigned short u16;
typedef unsigned int u32;
typedef __attribute__((ext_vector_type(8))) short bf16x8;   // 8 bf16 = 4 VGPR
typedef __attribute__((ext_vector_type(8))) unsigned short ushort8;
typedef __attribute__((ext_vector_type(4))) float f32x4;

__device__ __forceinline__ u16 f2bf(float f) {
  unsigned u = __float_as_uint(f);
  u += 0x7fffu + ((u >> 16) & 1u);      // round-to-nearest-even
  return (u16)(u >> 16);
}

// async global->LDS, 16B per lane. LDS dest = wave-uniform base + lane*16.
__device__ __forceinline__ void gl16(const void* g, void* l) {
  __builtin_amdgcn_global_load_lds(
      (const __attribute__((address_space(1))) u32*)g,
      (__attribute__((address_space(3))) u32*)l, 16, 0, 0);
}

// ---- fused transpose+convert for BOTH weights in one dispatch ----
// tile id < 8192: w1 [E][DIM][FFDIM] -> w1t [E][FFDIM][DIM]
// tile id >= 8192: w2 [E][FFDIM][DIM] -> w2t [E][DIM][FFDIM]
// 64x64 fp32 tile -> bf16 transposed (same verified body as k_tr64).
__global__ __launch_bounds__(256) void k_trw(const float* __restrict__ w1,
                                             const float* __restrict__ w2,
                                             u16* __restrict__ w1t,
                                             u16* __restrict__ w2t) {
  __shared__ float t[64][65];
  int tb = blockIdx.x;
  const float* src; u16* dst; int R, C;
  if (tb < 8192) { src = w1; dst = w1t; R = DIM; C = FFDIM; }
  else { tb -= 8192; src = w2; dst = w2t; R = FFDIM; C = DIM; }
  const int per = (R / 64) * (C / 64);          // 1024
  const int e = tb / per;
  const int t2 = tb - e * per;
  const int nx = C / 64;
  const int c0 = (t2 % nx) * 64, r0 = (t2 / nx) * 64;
  const size_t eoff = (size_t)e * R * C;
  const int tid = threadIdx.x;
  {
    const int rr = tid >> 4, c4 = (tid & 15) * 4;
#pragma unroll
    for (int i = 0; i < 4; i++) {
      float4 v = *(const float4*)(src + eoff + (size_t)(r0 + rr + 16 * i) * C + c0 + c4);
      t[rr + 16 * i][c4] = v.x; t[rr + 16 * i][c4 + 1] = v.y;
      t[rr + 16 * i][c4 + 2] = v.z; t[rr + 16 * i][c4 + 3] = v.w;
    }
  }
  __syncthreads();
  {
    const int seg = tid & 7;            // 8 bf16 chunk within a dst row
#pragma unroll
    for (int i = 0; i < 2; i++) {
      int cc = (tid >> 3) + 32 * i;     // dst row (= src col)
      ushort8 o;
#pragma unroll
      for (int j = 0; j < 8; j++) o[j] = f2bf(t[seg * 8 + j][cc]);
      *(ushort8*)(dst + eoff + (size_t)(c0 + cc) * R + r0 + seg * 8) = o;
    }
  }
}

// ---------- router (fp64 logits, top-2, fp32 softmax) + fused x fp32->bf16 ----------
__global__ __launch_bounds__(256) void k_router(const float* __restrict__ x,
                                                const float* __restrict__ rw,
                                                u16* __restrict__ xb,
                                                int* __restrict__ tki,
                                                float* __restrict__ tkw,
                                                int* __restrict__ counts) {
  int lane = threadIdx.x & 63;
  int tok = blockIdx.x * 4 + (threadIdx.x >> 6);   // one wave per token
  const float* xr = x + (size_t)tok * DIM;
  u16* xbr = xb + (size_t)tok * DIM;
  double acc[NEXP];
#pragma unroll
  for (int e = 0; e < NEXP; e++) acc[e] = 0.0;
  for (int i = lane * 4; i < DIM; i += 256) {
    float4 xv = *(const float4*)(xr + i);
    ushort4 o;
    o.x = f2bf(xv.x); o.y = f2bf(xv.y); o.z = f2bf(xv.z); o.w = f2bf(xv.w);
    *(ushort4*)(xbr + i) = o;
#pragma unroll
    for (int e = 0; e < NEXP; e++) {
      float4 wv = *(const float4*)(rw + e * DIM + i);
      acc[e] += (double)xv.x * (double)wv.x + (double)xv.y * (double)wv.y +
                (double)xv.z * (double)wv.z + (double)xv.w * (double)wv.w;
    }
  }
#pragma unroll
  for (int e = 0; e < NEXP; e++) {
#pragma unroll
    for (int off = 32; off > 0; off >>= 1) acc[e] += __shfl_down(acc[e], off);
  }
  if (lane == 0) {
    int i0 = 0; double v0 = acc[0];
#pragma unroll
    for (int e = 1; e < NEXP; e++) if (acc[e] > v0) { v0 = acc[e]; i0 = e; }
    int i1 = -1; double v1 = -1e300;
#pragma unroll
    for (int e = 0; e < NEXP; e++)
      if (e != i0 && acc[e] > v1) { v1 = acc[e]; i1 = e; }
    float d = expf((float)(v1 - v0));   // v1 <= v0
    float s = 1.f + d;
    tki[tok * 2] = i0; tki[tok * 2 + 1] = i1;
    tkw[tok * 2] = 1.f / s; tkw[tok * 2 + 1] = d / s;
    atomicAdd(&counts[i0], 1); atomicAdd(&counts[i1], 1);
  }
}

// scan + build 128-row M-tile table, parallel. tiles[t] = (expert, pair_base)
__global__ void k_scan(const int* __restrict__ counts, int* __restrict__ offs,
                       int* __restrict__ curs, int2* __restrict__ tiles,
                       int* __restrict__ ntiles) {
  __shared__ int soff[NEXP + 1];
  __shared__ int stil[NEXP + 1];
  const int lane = threadIdx.x;    // 64 threads
  if (lane == 0) {
    int s = 0, t = 0;
    for (int e = 0; e < NEXP; e++) {
      soff[e] = s; stil[e] = t;
      offs[e] = s; curs[e] = 0;
      s += counts[e]; t += (counts[e] + 127) >> 7;
    }
    soff[NEXP] = s; stil[NEXP] = t;
    offs[NEXP] = s; *ntiles = t;
  }
  __syncthreads();
  const int T = stil[NEXP];
  for (int t = lane; t < T; t += 64) {
    int e = 0;
#pragma unroll
    for (int q = 1; q < NEXP; q++) if (t >= stil[q]) e = q;
    int2 v; v.x = e; v.y = soff[e] + (t - stil[e]) * 128;
    tiles[t] = v;
  }
}

// scatter with per-block LDS aggregation: 8 global atomics per block (range
// reservation) instead of 512 device-scope atomics on 8 hot counters.
__global__ __launch_bounds__(256) void k_scatter(const int* __restrict__ tki,
                                                 const float* __restrict__ tkw,
                                                 const int* __restrict__ offs,
                                                 int* __restrict__ curs,
                                                 int* __restrict__ ptok,
                                                 float* __restrict__ pgate) {
  __shared__ int lcnt[NEXP], lbase[NEXP];
  const int tid = threadIdx.x;
  if (tid < NEXP) lcnt[tid] = 0;
  __syncthreads();
  int tok = blockIdx.x * 256 + tid;
  int e0 = tki[tok * 2], e1 = tki[tok * 2 + 1];
  int s0 = atomicAdd(&lcnt[e0], 1);
  int s1 = atomicAdd(&lcnt[e1], 1);
  __syncthreads();
  if (tid < NEXP) lbase[tid] = atomicAdd(&curs[tid], lcnt[tid]);
  __syncthreads();
  int pos0 = offs[e0] + lbase[e0] + s0;
  ptok[pos0] = tok; pgate[pos0] = tkw[tok * 2];
  int pos1 = offs[e1] + lbase[e1] + s1;
  ptok[pos1] = tok; pgate[pos1] = tkw[tok * 2 + 1];
}

// =====================================================================================
// grouped GEMM, r13 known-best (227us/GEMM, MfmaUtil 25.6%, FETCH ~172MB): 128x128
// tile, BK=64, 4 waves, single 32KB LDS buffer, 2-barrier drain K-loop,
// global_load_lds w=16, pre-swizzled global source + XOR-swizzled ds_read (rule #21).
// Empirical notes from r14-r16: counted-vmcnt dbuf and BK=128 both widen the in-flight
// load window -> FETCH 3x (L2 timing broken) + regression. Residency pinned ~8 waves/CU
// regardless of launch bounds (r13 A/B null). Do not re-widen without new evidence.
// XCD-bijective remap: all N-blocks of an M-tile co-reside on one XCD's L2.
// MODE 0: H[p][f] = gelu(x[tok(p)] @ w1t[e][f])          NY=32, K=1024
// MODE 1: out[tok(p)][d] += gate(p)*(H[p] @ w2t[e][d])   NY=8,  K=4096
// =====================================================================================
template <int MODE>
__global__ __launch_bounds__(256, 4) void k_gemm(const u16* __restrict__ Abase,
                                                 const u16* __restrict__ Ball,
                                                 const int* __restrict__ offs,
                                                 const int2* __restrict__ tiles,
                                                 const int* __restrict__ ntiles,
                                                 const int* __restrict__ ptok,
                                                 const float* __restrict__ pgate,
                                                 u16* __restrict__ Hout,
                                                 float* __restrict__ out) {
  constexpr int KSZ = (MODE == 0) ? DIM : FFDIM;
  constexpr int NSZ = (MODE == 0) ? FFDIM : DIM;
  constexpr int NY = NSZ / 128;                  // 32 / 8
  constexpr int NWG = MAXTILE * NY;              // 4608 / 1152 (both %8==0)
  constexpr int CPX = NWG / 8;

  // XCD-bijective remap, ny innermost: same-A blocks contiguous within an XCD chunk.
  const int orig = (int)blockIdx.y * MAXTILE + (int)blockIdx.x;
  const int wgid = (orig & 7) * CPX + (orig >> 3);
  const int mt = wgid / NY;
  const int ny = wgid - mt * NY;
  if (mt >= *ntiles) return;

  const int2 te = tiles[mt];
  const int e = te.x;
  const int pair_base = te.y;
  const int pair_last = offs[e + 1] - 1;
  const int n0 = ny * 128;

  __shared__ __align__(16) char lds[32768];
  char* ldsA = lds;
  char* ldsB = lds + 16384;

  const int tid = threadIdx.x;
  const int lane = tid & 63;
  const int w = tid >> 6;
  const int wm = w >> 1, wn = w & 1;             // 2x2 wave grid, wave output 64x64

  const u16* Bexp = Ball + (size_t)e * KSZ * NSZ;

  // swizzled 16B slot within a 128B row chunk: stored[r][s] = global[r][s ^ (r&7)]
  const int swz16 = ((lane & 7) ^ (lane >> 3)) << 4;

  // per-lane global source addresses (wave w covers tile rows [w*32, w*32+32))
  const char* aSrc[4];
  const char* bSrc[4];
#pragma unroll
  for (int i = 0; i < 4; i++) {
    int r = w * 32 + i * 8 + (lane >> 3);
    int p = pair_base + r; if (p > pair_last) p = pair_last;   // clamp tail
    int arow = (MODE == 0) ? ptok[p] : p;
    aSrc[i] = (const char*)(Abase + (size_t)arow * KSZ) + swz16;
    bSrc[i] = (const char*)(Bexp + (size_t)(n0 + r) * KSZ) + swz16;
  }

  f32x4 acc[4][4] = {};

  constexpr int NT = KSZ / 64;
#pragma unroll 1
  for (int kt = 0; kt < NT; ++kt) {
    __syncthreads();   // previous tile fully consumed
#pragma unroll
    for (int i = 0; i < 4; i++) {
      gl16(aSrc[i], ldsA + (w * 32 + i * 8) * 128);
      gl16(bSrc[i], ldsB + (w * 32 + i * 8) * 128);
      aSrc[i] += 128; bSrc[i] += 128;
    }
    __syncthreads();   // drains vmcnt(0): tile visible
#pragma unroll
    for (int kk = 0; kk < 2; kk++) {
      bf16x8 av[4], bv[4];
#pragma unroll
      for (int fm = 0; fm < 4; fm++) {
        int row = wm * 64 + fm * 16 + (lane & 15);
        int slot = (kk * 4 + (lane >> 4)) ^ (row & 7);
        av[fm] = *(const bf16x8*)(ldsA + row * 128 + slot * 16);
      }
#pragma unroll
      for (int fn = 0; fn < 4; fn++) {
        int row = wn * 64 + fn * 16 + (lane & 15);
        int slot = (kk * 4 + (lane >> 4)) ^ (row & 7);
        bv[fn] = *(const bf16x8*)(ldsB + row * 128 + slot * 16);
      }
#pragma unroll
      for (int fm = 0; fm < 4; fm++)
#pragma unroll
        for (int fn = 0; fn < 4; fn++)
          acc[fm][fn] = __builtin_amdgcn_mfma_f32_16x16x32_bf16(av[fm], bv[fn],
                                                                acc[fm][fn], 0, 0, 0);
    }
  }

  // ---- epilogue. C/D layout (m89-verified): col = lane&15, row = (lane>>4)*4 + j ----
  if (MODE == 0) {
    // Coalesced H write via per-wave LDS restage (padded 68-f32 rows).
    // FULLY UNROLLED m: acc indices stay compile-time (rule #20).
    __syncthreads();   // all waves done reading ldsA/ldsB before reuse
    float* lw = (float*)(lds + w * 4352);        // 16 rows x 68 f32, wave-private
#pragma unroll
    for (int m = 0; m < 4; m++) {
#pragma unroll
      for (int fn = 0; fn < 4; fn++)
#pragma unroll
        for (int j = 0; j < 4; j++)
          lw[(((lane >> 4) << 2) + j) * 68 + fn * 16 + (lane & 15)] = acc[m][fn][j];
      asm volatile("s_waitcnt lgkmcnt(0)" ::: "memory");  // wave-private ds ordering
      const int r = lane >> 2;                   // 0..15, 4 lanes per row
      const int c0 = (lane & 3) * 16;
      const int p = pair_base + wm * 64 + m * 16 + r;
      f32x4 v0 = *(const f32x4*)(lw + r * 68 + c0);
      f32x4 v1 = *(const f32x4*)(lw + r * 68 + c0 + 4);
      f32x4 v2 = *(const f32x4*)(lw + r * 68 + c0 + 8);
      f32x4 v3 = *(const f32x4*)(lw + r * 68 + c0 + 12);
      asm volatile("s_waitcnt lgkmcnt(0)" ::: "memory");
      if (p <= pair_last) {
        ushort8 o0, o1;
#pragma unroll
        for (int k = 0; k < 4; k++) {
          float h;
          h = v0[k]; o0[k]     = f2bf(0.5f * h * (1.f + erff(h * 0.70710678118654752f)));
          h = v1[k]; o0[k + 4] = f2bf(0.5f * h * (1.f + erff(h * 0.70710678118654752f)));
          h = v2[k]; o1[k]     = f2bf(0.5f * h * (1.f + erff(h * 0.70710678118654752f)));
          h = v3[k]; o1[k + 4] = f2bf(0.5f * h * (1.f + erff(h * 0.70710678118654752f)));
        }
        u16* hp = Hout + (size_t)p * FFDIM + n0 + wn * 64 + c0;
        *(ushort8*)hp = o0;
        *(ushort8*)(hp + 8) = o1;
      }
    }
  } else {
#pragma unroll
    for (int m = 0; m < 4; m++) {
      int rbase = wm * 64 + m * 16 + ((lane >> 4) << 2);
#pragma unroll
      for (int j = 0; j < 4; j++) {
        int p = pair_base + rbase + j;
        if (p > pair_last) continue;
        float gate = pgate[p];
        int tokr = ptok[p];
#pragma unroll
        for (int fn = 0; fn < 4; fn++) {
          int col = n0 + wn * 64 + fn * 16 + (lane & 15);
          atomicAdd(&out[(size_t)tokr * DIM + col], acc[m][fn][j] * gate);
        }
      }
    }
  }
}

// ---------------- launcher ----------------
extern "C" void kernel_launch(void* const* d_in, const int* in_sizes, int n_in,
                              void* d_out, int out_size, void* d_ws, size_t ws_size,
                              hipStream_t stream) {
  const float* x  = (const float*)d_in[0];
  const float* rw = (const float*)d_in[1];
  const float* w1 = (const float*)d_in[2];
  const float* w2 = (const float*)d_in[3];
  float* out = (float*)d_out;

  char* ws = (char*)d_ws;
  u16* xb   = (u16*)ws;  ws += (size_t)N_TOK * DIM * 2;          // 16.8 MB
  u16* w1t  = (u16*)ws;  ws += (size_t)NEXP * FFDIM * DIM * 2;   // 67 MB   [E][F][D]
  u16* w2t  = (u16*)ws;  ws += (size_t)NEXP * DIM * FFDIM * 2;   // 67 MB   [E][D][F]
  u16* H    = (u16*)ws;  ws += (size_t)NPAIR * FFDIM * 2;        // 134 MB  [NPAIR][F]
  int*   ptok  = (int*)ws;   ws += NPAIR * 4;
  float* pgate = (float*)ws; ws += NPAIR * 4;
  int*   tki   = (int*)ws;   ws += N_TOK * 2 * 4;
  float* tkw   = (float*)ws; ws += N_TOK * 2 * 4;
  int*   counts = (int*)ws;  ws += NEXP * 4;
  int*   offs   = (int*)ws;  ws += (NEXP + 1) * 4;
  int*   curs   = (int*)ws;  ws += NEXP * 4;
  int2*  tiles  = (int2*)ws; ws += MAXTILE * 8;
  int*   ntiles = (int*)ws;  ws += 4;

  hipMemsetAsync(counts, 0, (NEXP + (NEXP + 1) + NEXP) * 4, stream);
  hipMemsetAsync(d_out, 0, (size_t)N_TOK * DIM * 4, stream);

  k_router<<<N_TOK / 4, 256, 0, stream>>>(x, rw, xb, tki, tkw, counts);
  k_trw<<<16384, 256, 0, stream>>>(w1, w2, w1t, w2t);   // both weights, one dispatch
  k_scan<<<1, 64, 0, stream>>>(counts, offs, curs, tiles, ntiles);
  k_scatter<<<N_TOK / 256, 256, 0, stream>>>(tki, tkw, offs, curs, ptok, pgate);
  // fc1: NY=32 N-tiles; fc2: NY=8 N-tiles
  k_gemm<0><<<dim3(MAXTILE, 32), 256, 0, stream>>>(
      xb, w1t, offs, tiles, ntiles, ptok, pgate, H, nullptr);
  k_gemm<1><<<dim3(MAXTILE, 8), 256, 0, stream>>>(
      H, w2t, offs, tiles, ntiles, ptok, pgate, nullptr, out);
}

// Round 18
// 677.322 us; speedup vs baseline: 1.3251x; 1.0309x over previous
//
#include <hip/hip_runtime.h>
#include <hip/hip_bf16.h>

// MoE FFN: B=4,T=2048,D=1024,F=4096,E=8,topK=2 ; N=8192 tokens, NPAIR=16384
#define N_TOK  8192
#define DIM    1024
#define FFDIM  4096
#define NEXP   8
#define NPAIR  16384
#define MAXTILE 144   // >= sum_e ceil(cnt_e/128) <= 136

typedef unsigned short u16;
typedef unsigned int u32;
typedef __attribute__((ext_vector_type(8))) short bf16x8;   // 8 bf16 = 4 VGPR
typedef __attribute__((ext_vector_type(8))) unsigned short ushort8;
typedef __attribute__((ext_vector_type(4))) float f32x4;

__device__ __forceinline__ u16 f2bf(float f) {
  unsigned u = __float_as_uint(f);
  u += 0x7fffu + ((u >> 16) & 1u);      // round-to-nearest-even
  return (u16)(u >> 16);
}

// async global->LDS, 16B per lane. LDS dest = wave-uniform base + lane*16.
__device__ __forceinline__ void gl16(const void* g, void* l) {
  __builtin_amdgcn_global_load_lds(
      (const __attribute__((address_space(1))) u32*)g,
      (__attribute__((address_space(3))) u32*)l, 16, 0, 0);
}

// =====================================================================================
// k_pre: ONE dispatch covering both independent pre-pass jobs so they co-schedule:
//   blocks [0, 16384)      : weight transpose+convert (64x64 fp32 tile -> bf16 T)
//                            tb<8192: w1 [E][D][F]->w1t [E][F][D]; else w2 ->w2t
//   blocks [16384, 18432)  : router (1 wave/token, fp64 logits, top-2, fp32 softmax)
//                            + fused x fp32->bf16 conversion
// Router compute (~45us) hides under the BW-bound transpose (~110us).
// =====================================================================================
__global__ __launch_bounds__(256) void k_pre(const float* __restrict__ w1,
                                             const float* __restrict__ w2,
                                             u16* __restrict__ w1t,
                                             u16* __restrict__ w2t,
                                             const float* __restrict__ x,
                                             const float* __restrict__ rw,
                                             u16* __restrict__ xb,
                                             int* __restrict__ tki,
                                             float* __restrict__ tkw,
                                             int* __restrict__ counts) {
  __shared__ float t[64][65];
  const int tid = threadIdx.x;
  int tb = blockIdx.x;
  if (tb < 16384) {
    // ---- transpose+convert path (verified k_trw body) ----
    const float* src; u16* dst; int R, C;
    if (tb < 8192) { src = w1; dst = w1t; R = DIM; C = FFDIM; }
    else { tb -= 8192; src = w2; dst = w2t; R = FFDIM; C = DIM; }
    const int per = (R / 64) * (C / 64);          // 1024
    const int e = tb / per;
    const int t2 = tb - e * per;
    const int nx = C / 64;
    const int c0 = (t2 % nx) * 64, r0 = (t2 / nx) * 64;
    const size_t eoff = (size_t)e * R * C;
    {
      const int rr = tid >> 4, c4 = (tid & 15) * 4;
#pragma unroll
      for (int i = 0; i < 4; i++) {
        float4 v = *(const float4*)(src + eoff + (size_t)(r0 + rr + 16 * i) * C + c0 + c4);
        t[rr + 16 * i][c4] = v.x; t[rr + 16 * i][c4 + 1] = v.y;
        t[rr + 16 * i][c4 + 2] = v.z; t[rr + 16 * i][c4 + 3] = v.w;
      }
    }
    __syncthreads();
    {
      const int seg = tid & 7;            // 8 bf16 chunk within a dst row
#pragma unroll
      for (int i = 0; i < 2; i++) {
        int cc = (tid >> 3) + 32 * i;     // dst row (= src col)
        ushort8 o;
#pragma unroll
        for (int j = 0; j < 8; j++) o[j] = f2bf(t[seg * 8 + j][cc]);
        *(ushort8*)(dst + eoff + (size_t)(c0 + cc) * R + r0 + seg * 8) = o;
      }
    }
  } else {
    // ---- router path (verified k_router body) ----
    int lane = tid & 63;
    int tok = (tb - 16384) * 4 + (tid >> 6);     // one wave per token
    const float* xr = x + (size_t)tok * DIM;
    u16* xbr = xb + (size_t)tok * DIM;
    double acc[NEXP];
#pragma unroll
    for (int e = 0; e < NEXP; e++) acc[e] = 0.0;
    for (int i = lane * 4; i < DIM; i += 256) {
      float4 xv = *(const float4*)(xr + i);
      ushort4 o;
      o.x = f2bf(xv.x); o.y = f2bf(xv.y); o.z = f2bf(xv.z); o.w = f2bf(xv.w);
      *(ushort4*)(xbr + i) = o;
#pragma unroll
      for (int e = 0; e < NEXP; e++) {
        float4 wv = *(const float4*)(rw + e * DIM + i);
        acc[e] += (double)xv.x * (double)wv.x + (double)xv.y * (double)wv.y +
                  (double)xv.z * (double)wv.z + (double)xv.w * (double)wv.w;
      }
    }
#pragma unroll
    for (int e = 0; e < NEXP; e++) {
#pragma unroll
      for (int off = 32; off > 0; off >>= 1) acc[e] += __shfl_down(acc[e], off);
    }
    if (lane == 0) {
      int i0 = 0; double v0 = acc[0];
#pragma unroll
      for (int e = 1; e < NEXP; e++) if (acc[e] > v0) { v0 = acc[e]; i0 = e; }
      int i1 = -1; double v1 = -1e300;
#pragma unroll
      for (int e = 0; e < NEXP; e++)
        if (e != i0 && acc[e] > v1) { v1 = acc[e]; i1 = e; }
      float d = expf((float)(v1 - v0));   // v1 <= v0
      float s = 1.f + d;
      tki[tok * 2] = i0; tki[tok * 2 + 1] = i1;
      tkw[tok * 2] = 1.f / s; tkw[tok * 2 + 1] = d / s;
      atomicAdd(&counts[i0], 1); atomicAdd(&counts[i1], 1);
    }
  }
}

// scatter with per-block LDS aggregation; offsets computed inline from counts
// (8-entry prefix, fully-unrolled select loop — no runtime-indexed local arrays).
__global__ __launch_bounds__(256) void k_scatter(const int* __restrict__ tki,
                                                 const float* __restrict__ tkw,
                                                 const int* __restrict__ counts,
                                                 int* __restrict__ curs,
                                                 int* __restrict__ ptok,
                                                 float* __restrict__ pgate) {
  __shared__ int lcnt[NEXP], lbase[NEXP];
  const int tid = threadIdx.x;
  if (tid < NEXP) lcnt[tid] = 0;
  __syncthreads();
  int tok = blockIdx.x * 256 + tid;
  int e0 = tki[tok * 2], e1 = tki[tok * 2 + 1];
  int s0 = atomicAdd(&lcnt[e0], 1);
  int s1 = atomicAdd(&lcnt[e1], 1);
  __syncthreads();
  if (tid < NEXP) lbase[tid] = atomicAdd(&curs[tid], lcnt[tid]);
  __syncthreads();
  int off0 = 0, off1 = 0, s = 0;
#pragma unroll
  for (int q = 0; q < NEXP; q++) {
    if (q == e0) off0 = s;
    if (q == e1) off1 = s;
    s += counts[q];
  }
  int pos0 = off0 + lbase[e0] + s0;
  ptok[pos0] = tok; pgate[pos0] = tkw[tok * 2];
  int pos1 = off1 + lbase[e1] + s1;
  ptok[pos1] = tok; pgate[pos1] = tkw[tok * 2 + 1];
}

// =====================================================================================
// grouped GEMM, r13 known-best (227us/GEMM, MfmaUtil 25.6%, FETCH ~172MB): 128x128
// tile, BK=64, 4 waves, single 32KB LDS buffer, 2-barrier drain K-loop,
// global_load_lds w=16, pre-swizzled global source + XOR-swizzled ds_read (rule #21).
// Tile table REPLACED by inline mt->(expert, pair_base) decode from counts (unrolled
// select loop, no scratch arrays). r14-r16 lesson: do NOT widen the in-flight load
// window (dbuf / BK=128 -> 3x FETCH, L2 timing broken). XCD-bijective remap.
// MODE 0: H[p][f] = gelu(x[tok(p)] @ w1t[e][f])          NY=32, K=1024
// MODE 1: out[tok(p)][d] += gate(p)*(H[p] @ w2t[e][d])   NY=8,  K=4096
// =====================================================================================
template <int MODE>
__global__ __launch_bounds__(256, 4) void k_gemm(const u16* __restrict__ Abase,
                                                 const u16* __restrict__ Ball,
                                                 const int* __restrict__ counts,
                                                 const int* __restrict__ ptok,
                                                 const float* __restrict__ pgate,
                                                 u16* __restrict__ Hout,
                                                 float* __restrict__ out) {
  constexpr int KSZ = (MODE == 0) ? DIM : FFDIM;
  constexpr int NSZ = (MODE == 0) ? FFDIM : DIM;
  constexpr int NY = NSZ / 128;                  // 32 / 8
  constexpr int NWG = MAXTILE * NY;              // 4608 / 1152 (both %8==0)
  constexpr int CPX = NWG / 8;

  // XCD-bijective remap, ny innermost: same-A blocks contiguous within an XCD chunk.
  const int orig = (int)blockIdx.y * MAXTILE + (int)blockIdx.x;
  const int wgid = (orig & 7) * CPX + (orig >> 3);
  const int mt = wgid / NY;
  const int ny = wgid - mt * NY;

  // inline mt -> (expert, pair_base, pair_last); select-loop, all regs.
  int e = -1, pair_base = 0, pair_last = 0;
  {
    int s = 0, tt = 0;
#pragma unroll
    for (int q = 0; q < NEXP; q++) {
      int c = counts[q];
      int nt = (c + 127) >> 7;
      if (mt >= tt && mt < tt + nt) { e = q; pair_base = s + (mt - tt) * 128; pair_last = s + c - 1; }
      s += c; tt += nt;
    }
  }
  if (e < 0) return;                             // mt beyond last tile
  const int n0 = ny * 128;

  __shared__ __align__(16) char lds[32768];
  char* ldsA = lds;
  char* ldsB = lds + 16384;

  const int tid = threadIdx.x;
  const int lane = tid & 63;
  const int w = tid >> 6;
  const int wm = w >> 1, wn = w & 1;             // 2x2 wave grid, wave output 64x64

  const u16* Bexp = Ball + (size_t)e * KSZ * NSZ;

  // swizzled 16B slot within a 128B row chunk: stored[r][s] = global[r][s ^ (r&7)]
  const int swz16 = ((lane & 7) ^ (lane >> 3)) << 4;

  // per-lane global source addresses (wave w covers tile rows [w*32, w*32+32))
  const char* aSrc[4];
  const char* bSrc[4];
#pragma unroll
  for (int i = 0; i < 4; i++) {
    int r = w * 32 + i * 8 + (lane >> 3);
    int p = pair_base + r; if (p > pair_last) p = pair_last;   // clamp tail
    int arow = (MODE == 0) ? ptok[p] : p;
    aSrc[i] = (const char*)(Abase + (size_t)arow * KSZ) + swz16;
    bSrc[i] = (const char*)(Bexp + (size_t)(n0 + r) * KSZ) + swz16;
  }

  f32x4 acc[4][4] = {};

  constexpr int NT = KSZ / 64;
#pragma unroll 1
  for (int kt = 0; kt < NT; ++kt) {
    __syncthreads();   // previous tile fully consumed
#pragma unroll
    for (int i = 0; i < 4; i++) {
      gl16(aSrc[i], ldsA + (w * 32 + i * 8) * 128);
      gl16(bSrc[i], ldsB + (w * 32 + i * 8) * 128);
      aSrc[i] += 128; bSrc[i] += 128;
    }
    __syncthreads();   // drains vmcnt(0): tile visible
#pragma unroll
    for (int kk = 0; kk < 2; kk++) {
      bf16x8 av[4], bv[4];
#pragma unroll
      for (int fm = 0; fm < 4; fm++) {
        int row = wm * 64 + fm * 16 + (lane & 15);
        int slot = (kk * 4 + (lane >> 4)) ^ (row & 7);
        av[fm] = *(const bf16x8*)(ldsA + row * 128 + slot * 16);
      }
#pragma unroll
      for (int fn = 0; fn < 4; fn++) {
        int row = wn * 64 + fn * 16 + (lane & 15);
        int slot = (kk * 4 + (lane >> 4)) ^ (row & 7);
        bv[fn] = *(const bf16x8*)(ldsB + row * 128 + slot * 16);
      }
#pragma unroll
      for (int fm = 0; fm < 4; fm++)
#pragma unroll
        for (int fn = 0; fn < 4; fn++)
          acc[fm][fn] = __builtin_amdgcn_mfma_f32_16x16x32_bf16(av[fm], bv[fn],
                                                                acc[fm][fn], 0, 0, 0);
    }
  }

  // ---- epilogue. C/D layout (m89-verified): col = lane&15, row = (lane>>4)*4 + j ----
  if (MODE == 0) {
    // Coalesced H write via per-wave LDS restage (padded 68-f32 rows).
    // FULLY UNROLLED m: acc indices stay compile-time (rule #20).
    __syncthreads();   // all waves done reading ldsA/ldsB before reuse
    float* lw = (float*)(lds + w * 4352);        // 16 rows x 68 f32, wave-private
#pragma unroll
    for (int m = 0; m < 4; m++) {
#pragma unroll
      for (int fn = 0; fn < 4; fn++)
#pragma unroll
        for (int j = 0; j < 4; j++)
          lw[(((lane >> 4) << 2) + j) * 68 + fn * 16 + (lane & 15)] = acc[m][fn][j];
      asm volatile("s_waitcnt lgkmcnt(0)" ::: "memory");  // wave-private ds ordering
      const int r = lane >> 2;                   // 0..15, 4 lanes per row
      const int c0 = (lane & 3) * 16;
      const int p = pair_base + wm * 64 + m * 16 + r;
      f32x4 v0 = *(const f32x4*)(lw + r * 68 + c0);
      f32x4 v1 = *(const f32x4*)(lw + r * 68 + c0 + 4);
      f32x4 v2 = *(const f32x4*)(lw + r * 68 + c0 + 8);
      f32x4 v3 = *(const f32x4*)(lw + r * 68 + c0 + 12);
      asm volatile("s_waitcnt lgkmcnt(0)" ::: "memory");
      if (p <= pair_last) {
        ushort8 o0, o1;
#pragma unroll
        for (int k = 0; k < 4; k++) {
          float h;
          h = v0[k]; o0[k]     = f2bf(0.5f * h * (1.f + erff(h * 0.70710678118654752f)));
          h = v1[k]; o0[k + 4] = f2bf(0.5f * h * (1.f + erff(h * 0.70710678118654752f)));
          h = v2[k]; o1[k]     = f2bf(0.5f * h * (1.f + erff(h * 0.70710678118654752f)));
          h = v3[k]; o1[k + 4] = f2bf(0.5f * h * (1.f + erff(h * 0.70710678118654752f)));
        }
        u16* hp = Hout + (size_t)p * FFDIM + n0 + wn * 64 + c0;
        *(ushort8*)hp = o0;
        *(ushort8*)(hp + 8) = o1;
      }
    }
  } else {
#pragma unroll
    for (int m = 0; m < 4; m++) {
      int rbase = wm * 64 + m * 16 + ((lane >> 4) << 2);
#pragma unroll
      for (int j = 0; j < 4; j++) {
        int p = pair_base + rbase + j;
        if (p > pair_last) continue;
        float gate = pgate[p];
        int tokr = ptok[p];
#pragma unroll
        for (int fn = 0; fn < 4; fn++) {
          int col = n0 + wn * 64 + fn * 16 + (lane & 15);
          atomicAdd(&out[(size_t)tokr * DIM + col], acc[m][fn][j] * gate);
        }
      }
    }
  }
}

// ---------------- launcher ----------------
extern "C" void kernel_launch(void* const* d_in, const int* in_sizes, int n_in,
                              void* d_out, int out_size, void* d_ws, size_t ws_size,
                              hipStream_t stream) {
  const float* x  = (const float*)d_in[0];
  const float* rw = (const float*)d_in[1];
  const float* w1 = (const float*)d_in[2];
  const float* w2 = (const float*)d_in[3];
  float* out = (float*)d_out;

  char* ws = (char*)d_ws;
  u16* xb   = (u16*)ws;  ws += (size_t)N_TOK * DIM * 2;          // 16.8 MB
  u16* w1t  = (u16*)ws;  ws += (size_t)NEXP * FFDIM * DIM * 2;   // 67 MB   [E][F][D]
  u16* w2t  = (u16*)ws;  ws += (size_t)NEXP * DIM * FFDIM * 2;   // 67 MB   [E][D][F]
  u16* H    = (u16*)ws;  ws += (size_t)NPAIR * FFDIM * 2;        // 134 MB  [NPAIR][F]
  int*   ptok  = (int*)ws;   ws += NPAIR * 4;
  float* pgate = (float*)ws; ws += NPAIR * 4;
  int*   tki   = (int*)ws;   ws += N_TOK * 2 * 4;
  float* tkw   = (float*)ws; ws += N_TOK * 2 * 4;
  int*   counts = (int*)ws;  ws += NEXP * 4;
  int*   curs   = (int*)ws;  ws += NEXP * 4;

  hipMemsetAsync(counts, 0, 2 * NEXP * 4, stream);              // counts + curs
  hipMemsetAsync(d_out, 0, (size_t)N_TOK * DIM * 4, stream);

  // pre-pass: weight transposes (blocks 0..16383) + router (blocks 16384..18431)
  k_pre<<<16384 + N_TOK / 4, 256, 0, stream>>>(w1, w2, w1t, w2t,
                                               x, rw, xb, tki, tkw, counts);
  k_scatter<<<N_TOK / 256, 256, 0, stream>>>(tki, tkw, counts, curs, ptok, pgate);
  // fc1: NY=32 N-tiles; fc2: NY=8 N-tiles
  k_gemm<0><<<dim3(MAXTILE, 32), 256, 0, stream>>>(
      xb, w1t, counts, ptok, pgate, H, nullptr);
  k_gemm<1><<<dim3(MAXTILE, 8), 256, 0, stream>>>(
      H, w2t, counts, ptok, pgate, nullptr, out);
}

// Round 19
// 667.862 us; speedup vs baseline: 1.3439x; 1.0142x over previous
//
#include <hip/hip_runtime.h>
#include <hip/hip_bf16.h>

// MoE FFN: B=4,T=2048,D=1024,F=4096,E=8,topK=2 ; N=8192 tokens, NPAIR=16384
#define N_TOK  8192
#define DIM    1024
#define FFDIM  4096
#define NEXP   8
#define NPAIR  16384
#define MAXTILE 144   // >= sum_e ceil(cnt_e/128) <= 136

typedef unsigned short u16;
typedef unsigned int u32;
typedef __attribute__((ext_vector_type(8))) short bf16x8;   // 8 bf16 = 4 VGPR
typedef __attribute__((ext_vector_type(8))) unsigned short ushort8;
typedef __attribute__((ext_vector_type(4))) float f32x4;

__device__ __forceinline__ u16 f2bf(float f) {
  unsigned u = __float_as_uint(f);
  u += 0x7fffu + ((u >> 16) & 1u);      // round-to-nearest-even
  return (u16)(u >> 16);
}

// async global->LDS, 16B per lane. LDS dest = wave-uniform base + lane*16.
__device__ __forceinline__ void gl16(const void* g, void* l) {
  __builtin_amdgcn_global_load_lds(
      (const __attribute__((address_space(1))) u32*)g,
      (__attribute__((address_space(3))) u32*)l, 16, 0, 0);
}

// =====================================================================================
// k_pre: ONE dispatch, router FIRST so it overlaps the BW-bound transpose:
//   blocks [0, 2048)       : router (1 wave/token, fp64 logits, top-2, fp32 softmax)
//                            + fused x fp32->bf16 conversion
//   blocks [2048, 18432)   : weight transpose+convert (64x64 fp32 tile -> bf16 T)
//                            tb<8192: w1 [E][D][F]->w1t [E][F][D]; else w2 ->w2t
// r18 lesson: router blocks LAST ran as a serial tail (k_pre = trw+router summed).
// Transpose loads are batched (all 4 float4 issued before any LDS write) to raise
// memory-level parallelism — r18's load->LDS-write chain kept ~1 load in flight
// (530 GB/s fetch ~= Little's law at ~900cy HBM latency).
// =====================================================================================
__global__ __launch_bounds__(256) void k_pre(const float* __restrict__ w1,
                                             const float* __restrict__ w2,
                                             u16* __restrict__ w1t,
                                             u16* __restrict__ w2t,
                                             const float* __restrict__ x,
                                             const float* __restrict__ rw,
                                             u16* __restrict__ xb,
                                             int* __restrict__ tki,
                                             float* __restrict__ tkw,
                                             int* __restrict__ counts) {
  __shared__ float t[64][65];
  const int tid = threadIdx.x;
  int tb = blockIdx.x;
  if (tb < 2048) {
    // ---- router path (verified body) ----
    int lane = tid & 63;
    int tok = tb * 4 + (tid >> 6);               // one wave per token
    const float* xr = x + (size_t)tok * DIM;
    u16* xbr = xb + (size_t)tok * DIM;
    double acc[NEXP];
#pragma unroll
    for (int e = 0; e < NEXP; e++) acc[e] = 0.0;
    for (int i = lane * 4; i < DIM; i += 256) {
      float4 xv = *(const float4*)(xr + i);
      ushort4 o;
      o.x = f2bf(xv.x); o.y = f2bf(xv.y); o.z = f2bf(xv.z); o.w = f2bf(xv.w);
      *(ushort4*)(xbr + i) = o;
#pragma unroll
      for (int e = 0; e < NEXP; e++) {
        float4 wv = *(const float4*)(rw + e * DIM + i);
        acc[e] += (double)xv.x * (double)wv.x + (double)xv.y * (double)wv.y +
                  (double)xv.z * (double)wv.z + (double)xv.w * (double)wv.w;
      }
    }
#pragma unroll
    for (int e = 0; e < NEXP; e++) {
#pragma unroll
      for (int off = 32; off > 0; off >>= 1) acc[e] += __shfl_down(acc[e], off);
    }
    if (lane == 0) {
      int i0 = 0; double v0 = acc[0];
#pragma unroll
      for (int e = 1; e < NEXP; e++) if (acc[e] > v0) { v0 = acc[e]; i0 = e; }
      int i1 = -1; double v1 = -1e300;
#pragma unroll
      for (int e = 0; e < NEXP; e++)
        if (e != i0 && acc[e] > v1) { v1 = acc[e]; i1 = e; }
      float d = expf((float)(v1 - v0));   // v1 <= v0
      float s = 1.f + d;
      tki[tok * 2] = i0; tki[tok * 2 + 1] = i1;
      tkw[tok * 2] = 1.f / s; tkw[tok * 2 + 1] = d / s;
      atomicAdd(&counts[i0], 1); atomicAdd(&counts[i1], 1);
    }
  } else {
    // ---- transpose+convert path ----
    tb -= 2048;
    const float* src; u16* dst; int R, C;
    if (tb < 8192) { src = w1; dst = w1t; R = DIM; C = FFDIM; }
    else { tb -= 8192; src = w2; dst = w2t; R = FFDIM; C = DIM; }
    const int per = (R / 64) * (C / 64);          // 1024
    const int e = tb / per;
    const int t2 = tb - e * per;
    const int nx = C / 64;
    const int c0 = (t2 % nx) * 64, r0 = (t2 / nx) * 64;
    const size_t eoff = (size_t)e * R * C;
    {
      const int rr = tid >> 4, c4 = (tid & 15) * 4;
      float4 vv[4];                               // batch loads: 4 outstanding/thread
#pragma unroll
      for (int i = 0; i < 4; i++)
        vv[i] = *(const float4*)(src + eoff + (size_t)(r0 + rr + 16 * i) * C + c0 + c4);
#pragma unroll
      for (int i = 0; i < 4; i++) {
        t[rr + 16 * i][c4] = vv[i].x; t[rr + 16 * i][c4 + 1] = vv[i].y;
        t[rr + 16 * i][c4 + 2] = vv[i].z; t[rr + 16 * i][c4 + 3] = vv[i].w;
      }
    }
    __syncthreads();
    {
      const int seg = tid & 7;            // 8 bf16 chunk within a dst row
#pragma unroll
      for (int i = 0; i < 2; i++) {
        int cc = (tid >> 3) + 32 * i;     // dst row (= src col)
        ushort8 o;
#pragma unroll
        for (int j = 0; j < 8; j++) o[j] = f2bf(t[seg * 8 + j][cc]);
        *(ushort8*)(dst + eoff + (size_t)(c0 + cc) * R + r0 + seg * 8) = o;
      }
    }
  }
}

// scatter with per-block LDS aggregation; offsets computed inline from counts
// (8-entry prefix, fully-unrolled select loop — no runtime-indexed local arrays).
__global__ __launch_bounds__(256) void k_scatter(const int* __restrict__ tki,
                                                 const float* __restrict__ tkw,
                                                 const int* __restrict__ counts,
                                                 int* __restrict__ curs,
                                                 int* __restrict__ ptok,
                                                 float* __restrict__ pgate) {
  __shared__ int lcnt[NEXP], lbase[NEXP];
  const int tid = threadIdx.x;
  if (tid < NEXP) lcnt[tid] = 0;
  __syncthreads();
  int tok = blockIdx.x * 256 + tid;
  int e0 = tki[tok * 2], e1 = tki[tok * 2 + 1];
  int s0 = atomicAdd(&lcnt[e0], 1);
  int s1 = atomicAdd(&lcnt[e1], 1);
  __syncthreads();
  if (tid < NEXP) lbase[tid] = atomicAdd(&curs[tid], lcnt[tid]);
  __syncthreads();
  int off0 = 0, off1 = 0, s = 0;
#pragma unroll
  for (int q = 0; q < NEXP; q++) {
    if (q == e0) off0 = s;
    if (q == e1) off1 = s;
    s += counts[q];
  }
  int pos0 = off0 + lbase[e0] + s0;
  ptok[pos0] = tok; pgate[pos0] = tkw[tok * 2];
  int pos1 = off1 + lbase[e1] + s1;
  ptok[pos1] = tok; pgate[pos1] = tkw[tok * 2 + 1];
}

// =====================================================================================
// grouped GEMM, r13 known-best (227us/GEMM, MfmaUtil 25.6%, FETCH ~172MB): 128x128
// tile, BK=64, 4 waves, single 32KB LDS buffer, 2-barrier drain K-loop,
// global_load_lds w=16, pre-swizzled global source + XOR-swizzled ds_read (rule #21).
// Inline mt->(expert, pair_base) decode from counts (unrolled select loop).
// r14-r16 lesson: do NOT widen the in-flight load window (dbuf / BK=128 -> 3x FETCH,
// L2 timing broken). XCD-bijective remap.
// MODE 0: H[p][f] = gelu(x[tok(p)] @ w1t[e][f])          NY=32, K=1024
// MODE 1: out[tok(p)][d] += gate(p)*(H[p] @ w2t[e][d])   NY=8,  K=4096
// =====================================================================================
template <int MODE>
__global__ __launch_bounds__(256, 4) void k_gemm(const u16* __restrict__ Abase,
                                                 const u16* __restrict__ Ball,
                                                 const int* __restrict__ counts,
                                                 const int* __restrict__ ptok,
                                                 const float* __restrict__ pgate,
                                                 u16* __restrict__ Hout,
                                                 float* __restrict__ out) {
  constexpr int KSZ = (MODE == 0) ? DIM : FFDIM;
  constexpr int NSZ = (MODE == 0) ? FFDIM : DIM;
  constexpr int NY = NSZ / 128;                  // 32 / 8
  constexpr int NWG = MAXTILE * NY;              // 4608 / 1152 (both %8==0)
  constexpr int CPX = NWG / 8;

  // XCD-bijective remap, ny innermost: same-A blocks contiguous within an XCD chunk.
  const int orig = (int)blockIdx.y * MAXTILE + (int)blockIdx.x;
  const int wgid = (orig & 7) * CPX + (orig >> 3);
  const int mt = wgid / NY;
  const int ny = wgid - mt * NY;

  // inline mt -> (expert, pair_base, pair_last); select-loop, all regs.
  int e = -1, pair_base = 0, pair_last = 0;
  {
    int s = 0, tt = 0;
#pragma unroll
    for (int q = 0; q < NEXP; q++) {
      int c = counts[q];
      int nt = (c + 127) >> 7;
      if (mt >= tt && mt < tt + nt) { e = q; pair_base = s + (mt - tt) * 128; pair_last = s + c - 1; }
      s += c; tt += nt;
    }
  }
  if (e < 0) return;                             // mt beyond last tile
  const int n0 = ny * 128;

  __shared__ __align__(16) char lds[32768];
  char* ldsA = lds;
  char* ldsB = lds + 16384;

  const int tid = threadIdx.x;
  const int lane = tid & 63;
  const int w = tid >> 6;
  const int wm = w >> 1, wn = w & 1;             // 2x2 wave grid, wave output 64x64

  const u16* Bexp = Ball + (size_t)e * KSZ * NSZ;

  // swizzled 16B slot within a 128B row chunk: stored[r][s] = global[r][s ^ (r&7)]
  const int swz16 = ((lane & 7) ^ (lane >> 3)) << 4;

  // per-lane global source addresses (wave w covers tile rows [w*32, w*32+32))
  const char* aSrc[4];
  const char* bSrc[4];
#pragma unroll
  for (int i = 0; i < 4; i++) {
    int r = w * 32 + i * 8 + (lane >> 3);
    int p = pair_base + r; if (p > pair_last) p = pair_last;   // clamp tail
    int arow = (MODE == 0) ? ptok[p] : p;
    aSrc[i] = (const char*)(Abase + (size_t)arow * KSZ) + swz16;
    bSrc[i] = (const char*)(Bexp + (size_t)(n0 + r) * KSZ) + swz16;
  }

  f32x4 acc[4][4] = {};

  constexpr int NT = KSZ / 64;
#pragma unroll 1
  for (int kt = 0; kt < NT; ++kt) {
    __syncthreads();   // previous tile fully consumed
#pragma unroll
    for (int i = 0; i < 4; i++) {
      gl16(aSrc[i], ldsA + (w * 32 + i * 8) * 128);
      gl16(bSrc[i], ldsB + (w * 32 + i * 8) * 128);
      aSrc[i] += 128; bSrc[i] += 128;
    }
    __syncthreads();   // drains vmcnt(0): tile visible
#pragma unroll
    for (int kk = 0; kk < 2; kk++) {
      bf16x8 av[4], bv[4];
#pragma unroll
      for (int fm = 0; fm < 4; fm++) {
        int row = wm * 64 + fm * 16 + (lane & 15);
        int slot = (kk * 4 + (lane >> 4)) ^ (row & 7);
        av[fm] = *(const bf16x8*)(ldsA + row * 128 + slot * 16);
      }
#pragma unroll
      for (int fn = 0; fn < 4; fn++) {
        int row = wn * 64 + fn * 16 + (lane & 15);
        int slot = (kk * 4 + (lane >> 4)) ^ (row & 7);
        bv[fn] = *(const bf16x8*)(ldsB + row * 128 + slot * 16);
      }
#pragma unroll
      for (int fm = 0; fm < 4; fm++)
#pragma unroll
        for (int fn = 0; fn < 4; fn++)
          acc[fm][fn] = __builtin_amdgcn_mfma_f32_16x16x32_bf16(av[fm], bv[fn],
                                                                acc[fm][fn], 0, 0, 0);
    }
  }

  // ---- epilogue. C/D layout (m89-verified): col = lane&15, row = (lane>>4)*4 + j ----
  if (MODE == 0) {
    // Coalesced H write via per-wave LDS restage (padded 68-f32 rows).
    // FULLY UNROLLED m: acc indices stay compile-time (rule #20).
    __syncthreads();   // all waves done reading ldsA/ldsB before reuse
    float* lw = (float*)(lds + w * 4352);        // 16 rows x 68 f32, wave-private
#pragma unroll
    for (int m = 0; m < 4; m++) {
#pragma unroll
      for (int fn = 0; fn < 4; fn++)
#pragma unroll
        for (int j = 0; j < 4; j++)
          lw[(((lane >> 4) << 2) + j) * 68 + fn * 16 + (lane & 15)] = acc[m][fn][j];
      asm volatile("s_waitcnt lgkmcnt(0)" ::: "memory");  // wave-private ds ordering
      const int r = lane >> 2;                   // 0..15, 4 lanes per row
      const int c0 = (lane & 3) * 16;
      const int p = pair_base + wm * 64 + m * 16 + r;
      f32x4 v0 = *(const f32x4*)(lw + r * 68 + c0);
      f32x4 v1 = *(const f32x4*)(lw + r * 68 + c0 + 4);
      f32x4 v2 = *(const f32x4*)(lw + r * 68 + c0 + 8);
      f32x4 v3 = *(const f32x4*)(lw + r * 68 + c0 + 12);
      asm volatile("s_waitcnt lgkmcnt(0)" ::: "memory");
      if (p <= pair_last) {
        ushort8 o0, o1;
#pragma unroll
        for (int k = 0; k < 4; k++) {
          float h;
          h = v0[k]; o0[k]     = f2bf(0.5f * h * (1.f + erff(h * 0.70710678118654752f)));
          h = v1[k]; o0[k + 4] = f2bf(0.5f * h * (1.f + erff(h * 0.70710678118654752f)));
          h = v2[k]; o1[k]     = f2bf(0.5f * h * (1.f + erff(h * 0.70710678118654752f)));
          h = v3[k]; o1[k + 4] = f2bf(0.5f * h * (1.f + erff(h * 0.70710678118654752f)));
        }
        u16* hp = Hout + (size_t)p * FFDIM + n0 + wn * 64 + c0;
        *(ushort8*)hp = o0;
        *(ushort8*)(hp + 8) = o1;
      }
    }
  } else {
#pragma unroll
    for (int m = 0; m < 4; m++) {
      int rbase = wm * 64 + m * 16 + ((lane >> 4) << 2);
#pragma unroll
      for (int j = 0; j < 4; j++) {
        int p = pair_base + rbase + j;
        if (p > pair_last) continue;
        float gate = pgate[p];
        int tokr = ptok[p];
#pragma unroll
        for (int fn = 0; fn < 4; fn++) {
          int col = n0 + wn * 64 + fn * 16 + (lane & 15);
          atomicAdd(&out[(size_t)tokr * DIM + col], acc[m][fn][j] * gate);
        }
      }
    }
  }
}

// ---------------- launcher ----------------
extern "C" void kernel_launch(void* const* d_in, const int* in_sizes, int n_in,
                              void* d_out, int out_size, void* d_ws, size_t ws_size,
                              hipStream_t stream) {
  const float* x  = (const float*)d_in[0];
  const float* rw = (const float*)d_in[1];
  const float* w1 = (const float*)d_in[2];
  const float* w2 = (const float*)d_in[3];
  float* out = (float*)d_out;

  char* ws = (char*)d_ws;
  u16* xb   = (u16*)ws;  ws += (size_t)N_TOK * DIM * 2;          // 16.8 MB
  u16* w1t  = (u16*)ws;  ws += (size_t)NEXP * FFDIM * DIM * 2;   // 67 MB   [E][F][D]
  u16* w2t  = (u16*)ws;  ws += (size_t)NEXP * DIM * FFDIM * 2;   // 67 MB   [E][D][F]
  u16* H    = (u16*)ws;  ws += (size_t)NPAIR * FFDIM * 2;        // 134 MB  [NPAIR][F]
  int*   ptok  = (int*)ws;   ws += NPAIR * 4;
  float* pgate = (float*)ws; ws += NPAIR * 4;
  int*   tki   = (int*)ws;   ws += N_TOK * 2 * 4;
  float* tkw   = (float*)ws; ws += N_TOK * 2 * 4;
  int*   counts = (int*)ws;  ws += NEXP * 4;
  int*   curs   = (int*)ws;  ws += NEXP * 4;

  hipMemsetAsync(counts, 0, 2 * NEXP * 4, stream);              // counts + curs
  hipMemsetAsync(d_out, 0, (size_t)N_TOK * DIM * 4, stream);

  // pre-pass: router FIRST (blocks 0..2047), weight transposes after (2048..18431)
  k_pre<<<2048 + 16384, 256, 0, stream>>>(w1, w2, w1t, w2t,
                                          x, rw, xb, tki, tkw, counts);
  k_scatter<<<N_TOK / 256, 256, 0, stream>>>(tki, tkw, counts, curs, ptok, pgate);
  // fc1: NY=32 N-tiles; fc2: NY=8 N-tiles
  k_gemm<0><<<dim3(MAXTILE, 32), 256, 0, stream>>>(
      xb, w1t, counts, ptok, pgate, H, nullptr);
  k_gemm<1><<<dim3(MAXTILE, 8), 256, 0, stream>>>(
      H, w2t, counts, ptok, pgate, nullptr, out);
}